// Round 2
// baseline (448.309 us; speedup 1.0000x reference)
//
#include <hip/hip_runtime.h>
#include <math.h>

#define LN_EPS_ 1e-5f
#define INV_SQRT_DHEAD 0.17677669529663687f  // 1/sqrt(32)

// B=4, A=16, N=8, L=512, DE=256, DH=64, H=8, DHEAD=32, NL=4096

__device__ __forceinline__ float waveReduceSum(float v) {
    #pragma unroll
    for (int m = 32; m > 0; m >>= 1) v += __shfl_xor(v, m, 64);
    return v;
}
__device__ __forceinline__ float waveReduceMax(float v) {
    #pragma unroll
    for (int m = 32; m > 0; m >>= 1) v = fmaxf(v, __shfl_xor(v, m, 64));
    return v;
}

// ---------------------------------------------------------------------------
// Kernel 1: per (b,a): q = LN(curr_rho) @ Wq.T ; qk[h,e] = sum_dh q[h*32+dh]*Wk[h*32+dh,e]
// g[b,a,h,e] = ln_k_w[e]*qk ; s0 = sum_e g ; s2 = sum_e ln_k_b[e]*qk
// ---------------------------------------------------------------------------
__global__ __launch_bounds__(256) void k_prep(
    const float* __restrict__ curr_rho, const float* __restrict__ Wq,
    const float* __restrict__ Wk, const float* __restrict__ lnqw,
    const float* __restrict__ lnqb, const float* __restrict__ lnkw,
    const float* __restrict__ lnkb,
    float* __restrict__ g, float* __restrict__ s0, float* __restrict__ s2)
{
    __shared__ float xs[256];
    __shared__ float qs[256];
    __shared__ float red[8];
    const int t = threadIdx.x;
    const int w = t >> 6;
    const int ba = blockIdx.x;  // b*16+a
    const float x = curr_rho[(size_t)ba * 256 + t];

    float sm = waveReduceSum(x);
    if ((t & 63) == 0) red[w] = sm;
    __syncthreads();
    const float mu = (red[0] + red[1] + red[2] + red[3]) * (1.0f / 256.0f);
    __syncthreads();
    const float dx = x - mu;
    float sq = waveReduceSum(dx * dx);
    if ((t & 63) == 0) red[w] = sq;
    __syncthreads();
    const float var = (red[0] + red[1] + red[2] + red[3]) * (1.0f / 256.0f);
    const float rstd = 1.0f / sqrtf(var + LN_EPS_);
    __syncthreads();
    xs[t] = dx * rstd * lnqw[t] + lnqb[t];
    __syncthreads();

    // q[t] = dot(xs, Wq[t,:])
    {
        const float4* wq4 = (const float4*)(Wq + (size_t)t * 256);
        float acc = 0.f;
        #pragma unroll 8
        for (int e4 = 0; e4 < 64; ++e4) {
            float4 wv = wq4[e4];
            acc += xs[e4*4+0]*wv.x + xs[e4*4+1]*wv.y + xs[e4*4+2]*wv.z + xs[e4*4+3]*wv.w;
        }
        qs[t] = acc;
    }
    __syncthreads();

    for (int h = 0; h < 8; ++h) {
        float qk = 0.f;
        #pragma unroll 8
        for (int dh = 0; dh < 32; ++dh)
            qk += qs[h*32+dh] * Wk[(size_t)(h*32+dh)*256 + t];
        const float gv = lnkw[t] * qk;
        const float b2 = lnkb[t] * qk;
        g[((size_t)ba * 8 + h) * 256 + t] = gv;
        float sg = waveReduceSum(gv);
        float sb = waveReduceSum(b2);
        if ((t & 63) == 0) { red[w] = sg; red[4 + w] = sb; }
        __syncthreads();
        if (t == 0) {
            s0[ba*8+h] = red[0] + red[1] + red[2] + red[3];
            s2[ba*8+h] = red[4] + red[5] + red[6] + red[7];
        }
        __syncthreads();
    }
}

// ---------------------------------------------------------------------------
// Kernel 2: vals_tan0 = logmap0(demo_hyp)  (rows of 64; one wave per row)
// ---------------------------------------------------------------------------
__global__ __launch_bounds__(256) void k_vals(
    const float* __restrict__ demo_hyp, float* __restrict__ vals)
{
    const int t = threadIdx.x;
    const size_t idx = (size_t)blockIdx.x * 256 + t;
    const float x = demo_hyp[idx];
    const float ss = waveReduceSum(x * x);
    const float nrm = sqrtf(ss);
    const float n = fmaxf(nrm, 1e-15f);
    const float u = fminf(n, 1.0f - 1e-5f);
    const float f = atanhf(u) / n;
    vals[idx] = x * f;
}

// ---------------------------------------------------------------------------
// Kernel 3 (the streamer): scores[b,h,a,n,l] = (rstd*(S1 - mu*s0) + s2)/sqrt(32)
// Block = (b, a, n, 128 l's). 256 thr: half-wave (32 lanes) per row, 8 floats/lane.
// Reduction: FOLDING reduce-scatter butterfly — 12 shfl + 2 broadcasts instead of
// 50 shfl — lane h ends holding S1[h] fully reduced; lanes 8/9 hold sum/sumsq.
// Same pairwise-tree summation order as the full butterfly (bit-compatible).
// ---------------------------------------------------------------------------
__global__ __launch_bounds__(256) void k_scores(
    const float* __restrict__ demo_rho, const int* __restrict__ demo_mask,
    const float* __restrict__ g, const float* __restrict__ s0,
    const float* __restrict__ s2, float* __restrict__ attn)
{
    __shared__ float sbuf[8][132];
    const int t = threadIdx.x;
    const int gid = blockIdx.x;
    const int lc = gid & 3;
    const int n  = (gid >> 2) & 7;
    const int a  = (gid >> 5) & 15;
    const int b  = gid >> 9;
    const int c  = t & 31;   // column group (8 floats each)
    const int r  = t >> 5;   // row within pass (0..7)

    // g fragments -> registers (64 floats/lane)
    float gr[8][8];
    {
        const float* gb = g + ((size_t)(b*16 + a) * 8) * 256 + c * 8;
        #pragma unroll
        for (int h = 0; h < 8; ++h) {
            float4 ga = *(const float4*)(gb + h * 256);
            float4 gc = *(const float4*)(gb + h * 256 + 4);
            gr[h][0]=ga.x; gr[h][1]=ga.y; gr[h][2]=ga.z; gr[h][3]=ga.w;
            gr[h][4]=gc.x; gr[h][5]=gc.y; gr[h][6]=gc.z; gr[h][7]=gc.w;
        }
    }
    const float s0v = s0[(b*16 + a) * 8 + (c & 7)];
    const float s2v = s2[(b*16 + a) * 8 + (c & 7)];
    const int* mrow = demo_mask + (b*8 + n) * 512 + lc * 128;

    const float* xbase = demo_rho +
        ((size_t)((b*8 + n) * 512 + lc * 128) * 16 + a) * 256 + c * 8;

    #pragma unroll 2
    for (int p = 0; p < 16; ++p) {
        const float* xp = xbase + (size_t)(p * 8 + r) * 4096;  // row stride = A*DE
        float4 xa = *(const float4*)(xp);
        float4 xb = *(const float4*)(xp + 4);
        float xv[8] = {xa.x, xa.y, xa.z, xa.w, xb.x, xb.y, xb.z, xb.w};

        float v[10];
        #pragma unroll
        for (int h = 0; h < 8; ++h) {
            float acc = 0.f;
            #pragma unroll
            for (int j = 0; j < 8; ++j) acc += xv[j] * gr[h][j];
            v[h] = acc;
        }
        float sm = 0.f, sq = 0.f;
        #pragma unroll
        for (int j = 0; j < 8; ++j) { sm += xv[j]; sq += xv[j] * xv[j]; }
        v[8] = sm; v[9] = sq;

        // Folding reduce-scatter butterfly across 32 lanes.
        const int lb0 = c & 1, lb1 = c & 2, lb2 = c & 4, lb3 = c & 8;
        // m = 1: fold (0,1) (2,3) (4,5) (6,7) (8,9)
        float a0 = lb0 ? v[1] : v[0]; float q0 = lb0 ? v[0] : v[1];
        a0 += __shfl_xor(q0, 1, 32);
        float a1 = lb0 ? v[3] : v[2]; float q1 = lb0 ? v[2] : v[3];
        a1 += __shfl_xor(q1, 1, 32);
        float a2 = lb0 ? v[5] : v[4]; float q2 = lb0 ? v[4] : v[5];
        a2 += __shfl_xor(q2, 1, 32);
        float a3 = lb0 ? v[7] : v[6]; float q3 = lb0 ? v[6] : v[7];
        a3 += __shfl_xor(q3, 1, 32);
        float a4 = lb0 ? v[9] : v[8]; float q4 = lb0 ? v[8] : v[9];
        a4 += __shfl_xor(q4, 1, 32);
        // m = 2: fold (a0,a1) (a2,a3); plain a4
        float w0 = lb1 ? a1 : a0; float r0 = lb1 ? a0 : a1;
        w0 += __shfl_xor(r0, 2, 32);
        float w1 = lb1 ? a3 : a2; float r1 = lb1 ? a2 : a3;
        w1 += __shfl_xor(r1, 2, 32);
        float w2 = a4 + __shfl_xor(a4, 2, 32);
        // m = 4: fold (w0,w1); plain w2
        float x0 = lb2 ? w1 : w0; float r2 = lb2 ? w0 : w1;
        x0 += __shfl_xor(r2, 4, 32);
        float x1 = w2 + __shfl_xor(w2, 4, 32);
        // m = 8: fold (x0,x1)
        float y = lb3 ? x1 : x0; float r3 = lb3 ? x0 : x1;
        y += __shfl_xor(r3, 8, 32);
        // m = 16: plain
        y += __shfl_xor(y, 16, 32);
        // broadcasts: lane 8 holds sum(x), lane 9 holds sum(x^2)
        const float smv = __shfl(y, 8, 32);
        const float sqv = __shfl(y, 9, 32);

        if (c < 8) {
            const float mu   = smv * (1.0f / 256.0f);
            const float var  = sqv * (1.0f / 256.0f) - mu * mu;
            const float rstd = 1.0f / sqrtf(var + LN_EPS_);
            float sc = (rstd * (y - mu * s0v) + s2v) * INV_SQRT_DHEAD;
            const int lidx = p * 8 + r;
            if (mrow[lidx] == 0) sc = -INFINITY;
            sbuf[c][lidx] = sc;
        }
    }
    __syncthreads();
    // coalesced write of the 8x128 score tile
    {
        const int h = t >> 5;
        const float* rowp = &sbuf[h][0];
        float4 vout = *(const float4*)(rowp + c * 4);
        const size_t off = (size_t)((b*8 + h) * 16 + a) * 4096 + n * 512 + lc * 128 + c * 4;
        *(float4*)(attn + off) = vout;
    }
}

// ---------------------------------------------------------------------------
// Kernel 4: softmax over 4096 per (b,h,a) row (2 rows/block, processed by the
// two 256-thread halves CONCURRENTLY) + m_h = attn @ vals split over 8 waves.
// m_h p-reads are wave-uniform -> float4 broadcast ds_read_b128 (4x fewer DS
// instructions than scalar reads; DS pipe was this kernel's critical path).
// ---------------------------------------------------------------------------
__global__ __launch_bounds__(512) void k_softmax_mh(
    float* __restrict__ attn, const float* __restrict__ vals,
    float* __restrict__ mh)
{
    __shared__ float p0[4096];
    __shared__ float p1[4096];
    __shared__ float red[2][4];
    __shared__ float mpart[2][8][64];
    const int t = threadIdx.x;
    const int half = t >> 8;      // which row this half handles
    const int tt = t & 255;
    const int w = tt >> 6;        // wave within half
    const int row0 = blockIdx.x * 2;
    const int row = row0 + half;
    const int b = row0 >> 7;      // 128 rows per b

    float* dst = attn + (size_t)row * 4096;
    float* pl = half ? p1 : p0;

    float lmax = -INFINITY;
    float4 v4[4];
    #pragma unroll
    for (int k = 0; k < 4; ++k) {
        float4 vv = ((const float4*)dst)[k * 256 + tt];
        v4[k] = vv;
        lmax = fmaxf(lmax, fmaxf(fmaxf(vv.x, vv.y), fmaxf(vv.z, vv.w)));
    }
    lmax = waveReduceMax(lmax);
    if ((tt & 63) == 0) red[half][w] = lmax;
    __syncthreads();
    const float mx = fmaxf(fmaxf(red[half][0], red[half][1]),
                           fmaxf(red[half][2], red[half][3]));
    __syncthreads();
    float lsum = 0.f;
    #pragma unroll
    for (int k = 0; k < 4; ++k) {
        float4 vv = v4[k];
        vv.x = __expf(vv.x - mx); vv.y = __expf(vv.y - mx);
        vv.z = __expf(vv.z - mx); vv.w = __expf(vv.w - mx);
        v4[k] = vv;
        lsum += vv.x + vv.y + vv.z + vv.w;
    }
    lsum = waveReduceSum(lsum);
    if ((tt & 63) == 0) red[half][w] = lsum;
    __syncthreads();
    const float inv = 1.0f / (red[half][0] + red[half][1] +
                              red[half][2] + red[half][3]);
    #pragma unroll
    for (int k = 0; k < 4; ++k) {
        float4 vv = v4[k];
        vv.x *= inv; vv.y *= inv; vv.z *= inv; vv.w *= inv;
        ((float4*)pl)[k * 256 + tt] = vv;
        ((float4*)dst)[k * 256 + tt] = vv;
    }
    __syncthreads();

    // m_h: 8 waves, each owning a 512-wide x-chunk; p broadcast from LDS as
    // float4 (wave-uniform addr -> single ds_read_b128), vals coalesced
    // (64 consecutive d per wave).
    const int ch = t >> 6, d = t & 63;
    const float* vb = vals + (size_t)b * 262144 + d;
    float acc0a = 0.f, acc0b = 0.f, acc1a = 0.f, acc1b = 0.f;
    const int x0 = ch * 512;
    #pragma unroll 8
    for (int x = x0; x < x0 + 512; x += 4) {
        const float4 pa = *(const float4*)(p0 + x);
        const float4 pb = *(const float4*)(p1 + x);
        const float v0 = vb[(size_t)(x + 0) * 64];
        const float v1 = vb[(size_t)(x + 1) * 64];
        const float v2 = vb[(size_t)(x + 2) * 64];
        const float v3 = vb[(size_t)(x + 3) * 64];
        acc0a += pa.x * v0 + pa.z * v2;
        acc0b += pa.y * v1 + pa.w * v3;
        acc1a += pb.x * v0 + pb.z * v2;
        acc1b += pb.y * v1 + pb.w * v3;
    }
    mpart[0][ch][d] = acc0a + acc0b;
    mpart[1][ch][d] = acc1a + acc1b;
    __syncthreads();
    if (t < 128) {
        const int rr = t >> 6, dd = t & 63;
        float s = 0.f;
        #pragma unroll
        for (int cc = 0; cc < 8; ++cc) s += mpart[rr][cc][dd];
        mh[(size_t)(row0 + rr) * 64 + dd] = s;
    }
}

// ---------------------------------------------------------------------------
// Kernel 5: hyperbolic epilogue -> curr_hyp[b][64]; one wave per a (1024 thr!)
// ---------------------------------------------------------------------------
__global__ __launch_bounds__(1024) void k_final(
    const float* __restrict__ mh, float* __restrict__ out)
{
    __shared__ float contrib[16][64];
    const int t = threadIdx.x;
    const int a = t >> 6, d = t & 63;
    const int b = blockIdx.x;
    float accY = 0.f;
    #pragma unroll
    for (int h = 0; h < 8; ++h) {
        const float m = mh[(size_t)((b*8 + h) * 16 + a) * 64 + d];
        const float ss = waveReduceSum(m * m);
        const float nm = sqrtf(ss);
        const float n1 = fmaxf(nm, 1e-15f);
        const float t1 = tanhf(n1);
        const float e  = t1 * m / n1;
        const float ne = t1 * nm / n1;
        const float n2 = fmaxf(ne, 1e-15f);
        const float u  = fminf(n2, 1.0f - 1e-5f);
        accY += atanhf(u) * e / n2;
    }
    const float ym = accY * 0.125f;
    const float ssy = waveReduceSum(ym * ym);
    const float nmy = sqrtf(ssy);
    const float n3 = fmaxf(nmy, 1e-15f);
    const float t3 = tanhf(n3);
    const float chv = t3 * ym / n3;
    const float nch = t3 * nmy / n3;
    const float nrm = fmaxf(nch, 1e-6f);
    const float sc = fminf((1.0f - 1e-5f) / nrm, 1.0f);
    contrib[a][d] = chv * sc;
    __syncthreads();
    if (t < 64) {
        float s = 0.f;
        #pragma unroll
        for (int a2 = 0; a2 < 16; ++a2) s += contrib[a2][t];
        out[b * 64 + t] = s * (1.0f / 16.0f);
    }
}

// ---------------------------------------------------------------------------
extern "C" void kernel_launch(void* const* d_in, const int* in_sizes, int n_in,
                              void* d_out, int out_size, void* d_ws, size_t ws_size,
                              hipStream_t stream) {
    const float* curr_rho  = (const float*)d_in[0];
    const float* demo_rho  = (const float*)d_in[1];
    const float* demo_hyp  = (const float*)d_in[2];
    const int*   demo_mask = (const int*)d_in[3];
    const float* Wq   = (const float*)d_in[4];
    const float* Wk   = (const float*)d_in[5];
    const float* lnqw = (const float*)d_in[6];
    const float* lnqb = (const float*)d_in[7];
    const float* lnkw = (const float*)d_in[8];
    const float* lnkb = (const float*)d_in[9];

    float* out  = (float*)d_out;
    float* attn = out + 256;                 // curr_hyp first (B*DH=256), then attn

    float* ws   = (float*)d_ws;
    float* g    = ws;                        // 131072 floats
    float* s0   = ws + 131072;               // 512
    float* s2   = ws + 131584;               // 512
    float* vals = ws + 132096;               // 1048576
    float* mh   = ws + 1180672;              // 32768

    hipLaunchKernelGGL(k_prep, dim3(64), dim3(256), 0, stream,
                       curr_rho, Wq, Wk, lnqw, lnqb, lnkw, lnkb, g, s0, s2);
    hipLaunchKernelGGL(k_vals, dim3(4096), dim3(256), 0, stream, demo_hyp, vals);
    hipLaunchKernelGGL(k_scores, dim3(2048), dim3(256), 0, stream,
                       demo_rho, demo_mask, g, s0, s2, attn);
    hipLaunchKernelGGL(k_softmax_mh, dim3(256), dim3(512), 0, stream, attn, vals, mh);
    hipLaunchKernelGGL(k_final, dim3(4), dim3(1024), 0, stream, mh, out);
}

// Round 3
// 429.244 us; speedup vs baseline: 1.0444x; 1.0444x over previous
//
#include <hip/hip_runtime.h>
#include <math.h>

#define LN_EPS_ 1e-5f
#define INV_SQRT_DHEAD 0.17677669529663687f  // 1/sqrt(32)

// B=4, A=16, N=8, L=512, DE=256, DH=64, H=8, DHEAD=32, NL=4096

__device__ __forceinline__ float waveReduceSum(float v) {
    #pragma unroll
    for (int m = 32; m > 0; m >>= 1) v += __shfl_xor(v, m, 64);
    return v;
}
__device__ __forceinline__ float waveReduceMax(float v) {
    #pragma unroll
    for (int m = 32; m > 0; m >>= 1) v = fmaxf(v, __shfl_xor(v, m, 64));
    return v;
}

// ---------------------------------------------------------------------------
// Kernel 1 (merged): blocks [0,512): per (ba,h) prep — q = LN(curr_rho)@Wq.T
// recomputed per block (cheap, L2-resident Wq), then ONE h's qk/g/s0/s2.
// 8x more blocks than the old serial-h version -> latency head gone.
// blocks [512,4608): vals_tan0 = logmap0(demo_hyp), one wave per row of 64.
// Numerics identical to the previous split kernels (same summation orders).
// ---------------------------------------------------------------------------
__global__ __launch_bounds__(256) void k_prep_vals(
    const float* __restrict__ curr_rho, const float* __restrict__ Wq,
    const float* __restrict__ Wk, const float* __restrict__ lnqw,
    const float* __restrict__ lnqb, const float* __restrict__ lnkw,
    const float* __restrict__ lnkb, const float* __restrict__ demo_hyp,
    float* __restrict__ g, float* __restrict__ s0, float* __restrict__ s2,
    float* __restrict__ vals)
{
    __shared__ float xs[256];
    __shared__ float qs[256];
    __shared__ float red[8];
    const int t = threadIdx.x;
    const int bid = blockIdx.x;

    if (bid >= 512) {
        // ---- vals path (old k_vals) ----
        const size_t idx = (size_t)(bid - 512) * 256 + t;
        const float x = demo_hyp[idx];
        const float ss = waveReduceSum(x * x);
        const float nrm = sqrtf(ss);
        const float n = fmaxf(nrm, 1e-15f);
        const float u = fminf(n, 1.0f - 1e-5f);
        vals[idx] = x * (atanhf(u) / n);
        return;
    }

    // ---- prep path: one (ba, h) per block ----
    const int w = t >> 6;
    const int ba = bid >> 3;   // b*16+a
    const int h  = bid & 7;
    const float x = curr_rho[(size_t)ba * 256 + t];

    float sm = waveReduceSum(x);
    if ((t & 63) == 0) red[w] = sm;
    __syncthreads();
    const float mu = (red[0] + red[1] + red[2] + red[3]) * (1.0f / 256.0f);
    __syncthreads();
    const float dx = x - mu;
    float sq = waveReduceSum(dx * dx);
    if ((t & 63) == 0) red[w] = sq;
    __syncthreads();
    const float var = (red[0] + red[1] + red[2] + red[3]) * (1.0f / 256.0f);
    const float rstd = 1.0f / sqrtf(var + LN_EPS_);
    __syncthreads();
    xs[t] = dx * rstd * lnqw[t] + lnqb[t];
    __syncthreads();

    // q[t] = dot(xs, Wq[t,:])  (identical order to the old kernel)
    {
        const float4* wq4 = (const float4*)(Wq + (size_t)t * 256);
        float acc = 0.f;
        #pragma unroll 8
        for (int e4 = 0; e4 < 64; ++e4) {
            float4 wv = wq4[e4];
            acc += xs[e4*4+0]*wv.x + xs[e4*4+1]*wv.y + xs[e4*4+2]*wv.z + xs[e4*4+3]*wv.w;
        }
        qs[t] = acc;
    }
    __syncthreads();

    float qk = 0.f;
    #pragma unroll 8
    for (int dh = 0; dh < 32; ++dh)
        qk += qs[h*32+dh] * Wk[(size_t)(h*32+dh)*256 + t];
    const float gv = lnkw[t] * qk;
    const float b2 = lnkb[t] * qk;
    g[((size_t)ba * 8 + h) * 256 + t] = gv;
    float sg = waveReduceSum(gv);
    float sb = waveReduceSum(b2);
    if ((t & 63) == 0) { red[w] = sg; red[4 + w] = sb; }
    __syncthreads();
    if (t == 0) {
        s0[ba*8+h] = red[0] + red[1] + red[2] + red[3];
        s2[ba*8+h] = red[4] + red[5] + red[6] + red[7];
    }
}

// ---------------------------------------------------------------------------
// Kernel 3 (the streamer): scores[b,h,a,n,l] = (rstd*(S1 - mu*s0) + s2)/sqrt(32)
// Block = (b, a, n, 128 l's). 256 thr: half-wave (32 lanes) per row, 8 floats/lane.
// Reduction: FOLDING reduce-scatter butterfly — 12 shfl + 2 broadcasts.
// ---------------------------------------------------------------------------
__global__ __launch_bounds__(256) void k_scores(
    const float* __restrict__ demo_rho, const int* __restrict__ demo_mask,
    const float* __restrict__ g, const float* __restrict__ s0,
    const float* __restrict__ s2, float* __restrict__ attn)
{
    __shared__ float sbuf[8][132];
    const int t = threadIdx.x;
    const int gid = blockIdx.x;
    const int lc = gid & 3;
    const int n  = (gid >> 2) & 7;
    const int a  = (gid >> 5) & 15;
    const int b  = gid >> 9;
    const int c  = t & 31;   // column group (8 floats each)
    const int r  = t >> 5;   // row within pass (0..7)

    // g fragments -> registers (64 floats/lane)
    float gr[8][8];
    {
        const float* gb = g + ((size_t)(b*16 + a) * 8) * 256 + c * 8;
        #pragma unroll
        for (int h = 0; h < 8; ++h) {
            float4 ga = *(const float4*)(gb + h * 256);
            float4 gc = *(const float4*)(gb + h * 256 + 4);
            gr[h][0]=ga.x; gr[h][1]=ga.y; gr[h][2]=ga.z; gr[h][3]=ga.w;
            gr[h][4]=gc.x; gr[h][5]=gc.y; gr[h][6]=gc.z; gr[h][7]=gc.w;
        }
    }
    const float s0v = s0[(b*16 + a) * 8 + (c & 7)];
    const float s2v = s2[(b*16 + a) * 8 + (c & 7)];
    const int* mrow = demo_mask + (b*8 + n) * 512 + lc * 128;

    const float* xbase = demo_rho +
        ((size_t)((b*8 + n) * 512 + lc * 128) * 16 + a) * 256 + c * 8;

    #pragma unroll 2
    for (int p = 0; p < 16; ++p) {
        const float* xp = xbase + (size_t)(p * 8 + r) * 4096;  // row stride = A*DE
        float4 xa = *(const float4*)(xp);
        float4 xb = *(const float4*)(xp + 4);
        float xv[8] = {xa.x, xa.y, xa.z, xa.w, xb.x, xb.y, xb.z, xb.w};

        float v[10];
        #pragma unroll
        for (int h = 0; h < 8; ++h) {
            float acc = 0.f;
            #pragma unroll
            for (int j = 0; j < 8; ++j) acc += xv[j] * gr[h][j];
            v[h] = acc;
        }
        float sm = 0.f, sq = 0.f;
        #pragma unroll
        for (int j = 0; j < 8; ++j) { sm += xv[j]; sq += xv[j] * xv[j]; }
        v[8] = sm; v[9] = sq;

        // Folding reduce-scatter butterfly across 32 lanes.
        const int lb0 = c & 1, lb1 = c & 2, lb2 = c & 4, lb3 = c & 8;
        float a0 = lb0 ? v[1] : v[0]; float q0 = lb0 ? v[0] : v[1];
        a0 += __shfl_xor(q0, 1, 32);
        float a1 = lb0 ? v[3] : v[2]; float q1 = lb0 ? v[2] : v[3];
        a1 += __shfl_xor(q1, 1, 32);
        float a2 = lb0 ? v[5] : v[4]; float q2 = lb0 ? v[4] : v[5];
        a2 += __shfl_xor(q2, 1, 32);
        float a3 = lb0 ? v[7] : v[6]; float q3 = lb0 ? v[6] : v[7];
        a3 += __shfl_xor(q3, 1, 32);
        float a4 = lb0 ? v[9] : v[8]; float q4 = lb0 ? v[8] : v[9];
        a4 += __shfl_xor(q4, 1, 32);
        float w0 = lb1 ? a1 : a0; float r0 = lb1 ? a0 : a1;
        w0 += __shfl_xor(r0, 2, 32);
        float w1 = lb1 ? a3 : a2; float r1 = lb1 ? a2 : a3;
        w1 += __shfl_xor(r1, 2, 32);
        float w2 = a4 + __shfl_xor(a4, 2, 32);
        float x0 = lb2 ? w1 : w0; float r2 = lb2 ? w0 : w1;
        x0 += __shfl_xor(r2, 4, 32);
        float x1 = w2 + __shfl_xor(w2, 4, 32);
        float y = lb3 ? x1 : x0; float r3 = lb3 ? x0 : x1;
        y += __shfl_xor(r3, 8, 32);
        y += __shfl_xor(y, 16, 32);
        const float smv = __shfl(y, 8, 32);
        const float sqv = __shfl(y, 9, 32);

        if (c < 8) {
            const float mu   = smv * (1.0f / 256.0f);
            const float var  = sqv * (1.0f / 256.0f) - mu * mu;
            const float rstd = 1.0f / sqrtf(var + LN_EPS_);
            float sc = (rstd * (y - mu * s0v) + s2v) * INV_SQRT_DHEAD;
            const int lidx = p * 8 + r;
            if (mrow[lidx] == 0) sc = -INFINITY;
            sbuf[c][lidx] = sc;
        }
    }
    __syncthreads();
    // coalesced write of the 8x128 score tile
    {
        const int h = t >> 5;
        const float* rowp = &sbuf[h][0];
        float4 vout = *(const float4*)(rowp + c * 4);
        const size_t off = (size_t)((b*8 + h) * 16 + a) * 4096 + n * 512 + lc * 128 + c * 4;
        *(float4*)(attn + off) = vout;
    }
}

// ---------------------------------------------------------------------------
// Kernel 4: softmax over 4096 per (b,h,a) row (2 rows/block, two 256-thread
// halves concurrently) + m_h = attn @ vals split over 8 waves.
// Block->row map is XCD-clustered: each of the 8 XCDs processes exactly one
// b's rows (2 XCDs per b), so that b's 1 MB vals chunk stays L2-resident on
// that XCD instead of every XCD caching all 4 MB against the attn stream.
// ---------------------------------------------------------------------------
__global__ __launch_bounds__(512) void k_softmax_mh(
    float* __restrict__ attn, const float* __restrict__ vals,
    float* __restrict__ mh)
{
    __shared__ float p0[4096];
    __shared__ float p1[4096];
    __shared__ float red[2][4];
    __shared__ float mpart[2][8][64];
    const int t = threadIdx.x;
    const int half = t >> 8;      // which row this half handles
    const int tt = t & 255;
    const int w = tt >> 6;        // wave within half
    // XCD-clustered bijective remap: j%8 -> XCD (round-robin dispatch)
    const int j = blockIdx.x;
    const int xcd = j & 7, slot = j >> 3;                    // 32 slots/XCD
    const int rp = (xcd >> 1) * 64 + (xcd & 1) * 32 + slot;  // row-pair, b = rp>>6
    const int row0 = rp * 2;
    const int row = row0 + half;
    const int b = row0 >> 7;      // 128 rows per b

    float* dst = attn + (size_t)row * 4096;
    float* pl = half ? p1 : p0;

    float lmax = -INFINITY;
    float4 v4[4];
    #pragma unroll
    for (int k = 0; k < 4; ++k) {
        float4 vv = ((const float4*)dst)[k * 256 + tt];
        v4[k] = vv;
        lmax = fmaxf(lmax, fmaxf(fmaxf(vv.x, vv.y), fmaxf(vv.z, vv.w)));
    }
    lmax = waveReduceMax(lmax);
    if ((tt & 63) == 0) red[half][w] = lmax;
    __syncthreads();
    const float mx = fmaxf(fmaxf(red[half][0], red[half][1]),
                           fmaxf(red[half][2], red[half][3]));
    __syncthreads();
    float lsum = 0.f;
    #pragma unroll
    for (int k = 0; k < 4; ++k) {
        float4 vv = v4[k];
        vv.x = __expf(vv.x - mx); vv.y = __expf(vv.y - mx);
        vv.z = __expf(vv.z - mx); vv.w = __expf(vv.w - mx);
        v4[k] = vv;
        lsum += vv.x + vv.y + vv.z + vv.w;
    }
    lsum = waveReduceSum(lsum);
    if ((tt & 63) == 0) red[half][w] = lsum;
    __syncthreads();
    const float inv = 1.0f / (red[half][0] + red[half][1] +
                              red[half][2] + red[half][3]);
    #pragma unroll
    for (int k = 0; k < 4; ++k) {
        float4 vv = v4[k];
        vv.x *= inv; vv.y *= inv; vv.z *= inv; vv.w *= inv;
        ((float4*)pl)[k * 256 + tt] = vv;
        ((float4*)dst)[k * 256 + tt] = vv;
    }
    __syncthreads();

    // m_h: 8 waves, each owning a 512-wide x-chunk; p broadcast from LDS,
    // vals coalesced (64 consecutive d per wave).  (R1 version — best measured.)
    const int ch = t >> 6, d = t & 63;
    const float* vb = vals + (size_t)b * 262144 + d;
    float acc0a = 0.f, acc0b = 0.f, acc1a = 0.f, acc1b = 0.f;
    const int x0 = ch * 512;
    #pragma unroll 16
    for (int x = x0; x < x0 + 512; x += 2) {
        const float va = vb[(size_t)x * 64];
        const float vc = vb[(size_t)(x + 1) * 64];
        acc0a += p0[x] * va;     acc0b += p0[x + 1] * vc;
        acc1a += p1[x] * va;     acc1b += p1[x + 1] * vc;
    }
    mpart[0][ch][d] = acc0a + acc0b;
    mpart[1][ch][d] = acc1a + acc1b;
    __syncthreads();
    if (t < 128) {
        const int rr = t >> 6, dd = t & 63;
        float s = 0.f;
        #pragma unroll
        for (int cc = 0; cc < 8; ++cc) s += mpart[rr][cc][dd];
        mh[(size_t)(row0 + rr) * 64 + dd] = s;
    }
}

// ---------------------------------------------------------------------------
// Kernel 5: hyperbolic epilogue -> curr_hyp[b][64]; one wave per a (1024 thr!)
// ---------------------------------------------------------------------------
__global__ __launch_bounds__(1024) void k_final(
    const float* __restrict__ mh, float* __restrict__ out)
{
    __shared__ float contrib[16][64];
    const int t = threadIdx.x;
    const int a = t >> 6, d = t & 63;
    const int b = blockIdx.x;
    float accY = 0.f;
    #pragma unroll
    for (int h = 0; h < 8; ++h) {
        const float m = mh[(size_t)((b*8 + h) * 16 + a) * 64 + d];
        const float ss = waveReduceSum(m * m);
        const float nm = sqrtf(ss);
        const float n1 = fmaxf(nm, 1e-15f);
        const float t1 = tanhf(n1);
        const float e  = t1 * m / n1;
        const float ne = t1 * nm / n1;
        const float n2 = fmaxf(ne, 1e-15f);
        const float u  = fminf(n2, 1.0f - 1e-5f);
        accY += atanhf(u) * e / n2;
    }
    const float ym = accY * 0.125f;
    const float ssy = waveReduceSum(ym * ym);
    const float nmy = sqrtf(ssy);
    const float n3 = fmaxf(nmy, 1e-15f);
    const float t3 = tanhf(n3);
    const float chv = t3 * ym / n3;
    const float nch = t3 * nmy / n3;
    const float nrm = fmaxf(nch, 1e-6f);
    const float sc = fminf((1.0f - 1e-5f) / nrm, 1.0f);
    contrib[a][d] = chv * sc;
    __syncthreads();
    if (t < 64) {
        float s = 0.f;
        #pragma unroll
        for (int a2 = 0; a2 < 16; ++a2) s += contrib[a2][t];
        out[b * 64 + t] = s * (1.0f / 16.0f);
    }
}

// ---------------------------------------------------------------------------
extern "C" void kernel_launch(void* const* d_in, const int* in_sizes, int n_in,
                              void* d_out, int out_size, void* d_ws, size_t ws_size,
                              hipStream_t stream) {
    const float* curr_rho  = (const float*)d_in[0];
    const float* demo_rho  = (const float*)d_in[1];
    const float* demo_hyp  = (const float*)d_in[2];
    const int*   demo_mask = (const int*)d_in[3];
    const float* Wq   = (const float*)d_in[4];
    const float* Wk   = (const float*)d_in[5];
    const float* lnqw = (const float*)d_in[6];
    const float* lnqb = (const float*)d_in[7];
    const float* lnkw = (const float*)d_in[8];
    const float* lnkb = (const float*)d_in[9];

    float* out  = (float*)d_out;
    float* attn = out + 256;                 // curr_hyp first (B*DH=256), then attn

    float* ws   = (float*)d_ws;
    float* g    = ws;                        // 131072 floats
    float* s0   = ws + 131072;               // 512
    float* s2   = ws + 131584;               // 512
    float* vals = ws + 132096;               // 1048576
    float* mh   = ws + 1180672;              // 32768

    hipLaunchKernelGGL(k_prep_vals, dim3(4608), dim3(256), 0, stream,
                       curr_rho, Wq, Wk, lnqw, lnqb, lnkw, lnkb, demo_hyp,
                       g, s0, s2, vals);
    hipLaunchKernelGGL(k_scores, dim3(2048), dim3(256), 0, stream,
                       demo_rho, demo_mask, g, s0, s2, attn);
    hipLaunchKernelGGL(k_softmax_mh, dim3(256), dim3(512), 0, stream, attn, vals, mh);
    hipLaunchKernelGGL(k_final, dim3(4), dim3(1024), 0, stream, mh, out);
}

// Round 4
// 427.014 us; speedup vs baseline: 1.0499x; 1.0052x over previous
//
#include <hip/hip_runtime.h>
#include <math.h>

#define LN_EPS_ 1e-5f
#define INV_SQRT_DHEAD 0.17677669529663687f  // 1/sqrt(32)

// B=4, A=16, N=8, L=512, DE=256, DH=64, H=8, DHEAD=32, NL=4096

__device__ __forceinline__ float waveReduceSum(float v) {
    #pragma unroll
    for (int m = 32; m > 0; m >>= 1) v += __shfl_xor(v, m, 64);
    return v;
}
__device__ __forceinline__ float waveReduceMax(float v) {
    #pragma unroll
    for (int m = 32; m > 0; m >>= 1) v = fmaxf(v, __shfl_xor(v, m, 64));
    return v;
}

// ---------------------------------------------------------------------------
// Kernel 1: per (ba,h) prep — q = LN(curr_rho)@Wq.T recomputed per block
// (cheap, L2-resident Wq), then ONE h's qk/g/s0/s2. 512 blocks -> 2 blocks/CU,
// no serial h-loop, retires in ~3 us.
// ---------------------------------------------------------------------------
__global__ __launch_bounds__(256) void k_prep(
    const float* __restrict__ curr_rho, const float* __restrict__ Wq,
    const float* __restrict__ Wk, const float* __restrict__ lnqw,
    const float* __restrict__ lnqb, const float* __restrict__ lnkw,
    const float* __restrict__ lnkb,
    float* __restrict__ g, float* __restrict__ s0, float* __restrict__ s2)
{
    __shared__ float xs[256];
    __shared__ float qs[256];
    __shared__ float red[8];
    const int t = threadIdx.x;
    const int w = t >> 6;
    const int ba = blockIdx.x >> 3;   // b*16+a
    const int h  = blockIdx.x & 7;
    const float x = curr_rho[(size_t)ba * 256 + t];

    float sm = waveReduceSum(x);
    if ((t & 63) == 0) red[w] = sm;
    __syncthreads();
    const float mu = (red[0] + red[1] + red[2] + red[3]) * (1.0f / 256.0f);
    __syncthreads();
    const float dx = x - mu;
    float sq = waveReduceSum(dx * dx);
    if ((t & 63) == 0) red[w] = sq;
    __syncthreads();
    const float var = (red[0] + red[1] + red[2] + red[3]) * (1.0f / 256.0f);
    const float rstd = 1.0f / sqrtf(var + LN_EPS_);
    __syncthreads();
    xs[t] = dx * rstd * lnqw[t] + lnqb[t];
    __syncthreads();

    // q[t] = dot(xs, Wq[t,:])  (identical order to the old kernel)
    {
        const float4* wq4 = (const float4*)(Wq + (size_t)t * 256);
        float acc = 0.f;
        #pragma unroll 8
        for (int e4 = 0; e4 < 64; ++e4) {
            float4 wv = wq4[e4];
            acc += xs[e4*4+0]*wv.x + xs[e4*4+1]*wv.y + xs[e4*4+2]*wv.z + xs[e4*4+3]*wv.w;
        }
        qs[t] = acc;
    }
    __syncthreads();

    float qk = 0.f;
    #pragma unroll 8
    for (int dh = 0; dh < 32; ++dh)
        qk += qs[h*32+dh] * Wk[(size_t)(h*32+dh)*256 + t];
    const float gv = lnkw[t] * qk;
    const float b2 = lnkb[t] * qk;
    g[((size_t)ba * 8 + h) * 256 + t] = gv;
    float sg = waveReduceSum(gv);
    float sb = waveReduceSum(b2);
    if ((t & 63) == 0) { red[w] = sg; red[4 + w] = sb; }
    __syncthreads();
    if (t == 0) {
        s0[ba*8+h] = red[0] + red[1] + red[2] + red[3];
        s2[ba*8+h] = red[4] + red[5] + red[6] + red[7];
    }
}

// ---------------------------------------------------------------------------
// Kernel 2 (merged streamer): blocks [0,2048) compute scores; blocks
// [2048,6144) compute vals = logmap0(demo_hyp). The vals work (VALU-heavy,
// tiny traffic) hides completely under the scores blocks' HBM streaming —
// the scores path leaves the VALU pipes mostly idle. k_softmax_mh needs both
// products, so the dependency structure is unchanged.
// scores[b,h,a,n,l] = (rstd*(S1 - mu*s0) + s2)/sqrt(32)
// Block = (b, a, n, 128 l's). 256 thr: half-wave (32 lanes) per row,
// 8 floats/lane; FOLDING reduce-scatter butterfly (12 shfl + 2 broadcasts).
// ---------------------------------------------------------------------------
__global__ __launch_bounds__(256) void k_scores_vals(
    const float* __restrict__ demo_rho, const int* __restrict__ demo_mask,
    const float* __restrict__ g, const float* __restrict__ s0,
    const float* __restrict__ s2, const float* __restrict__ demo_hyp,
    float* __restrict__ attn, float* __restrict__ vals)
{
    __shared__ float sbuf[8][132];
    const int t = threadIdx.x;
    const int gid = blockIdx.x;

    if (gid >= 2048) {
        // ---- vals path ----
        const size_t idx = (size_t)(gid - 2048) * 256 + t;
        const float x = demo_hyp[idx];
        const float ss = waveReduceSum(x * x);
        const float nrm = sqrtf(ss);
        const float n = fmaxf(nrm, 1e-15f);
        const float u = fminf(n, 1.0f - 1e-5f);
        vals[idx] = x * (atanhf(u) / n);
        return;
    }

    const int lc = gid & 3;
    const int n  = (gid >> 2) & 7;
    const int a  = (gid >> 5) & 15;
    const int b  = gid >> 9;
    const int c  = t & 31;   // column group (8 floats each)
    const int r  = t >> 5;   // row within pass (0..7)

    // g fragments -> registers (64 floats/lane)
    float gr[8][8];
    {
        const float* gb = g + ((size_t)(b*16 + a) * 8) * 256 + c * 8;
        #pragma unroll
        for (int h = 0; h < 8; ++h) {
            float4 ga = *(const float4*)(gb + h * 256);
            float4 gc = *(const float4*)(gb + h * 256 + 4);
            gr[h][0]=ga.x; gr[h][1]=ga.y; gr[h][2]=ga.z; gr[h][3]=ga.w;
            gr[h][4]=gc.x; gr[h][5]=gc.y; gr[h][6]=gc.z; gr[h][7]=gc.w;
        }
    }
    const float s0v = s0[(b*16 + a) * 8 + (c & 7)];
    const float s2v = s2[(b*16 + a) * 8 + (c & 7)];
    const int* mrow = demo_mask + (b*8 + n) * 512 + lc * 128;

    const float* xbase = demo_rho +
        ((size_t)((b*8 + n) * 512 + lc * 128) * 16 + a) * 256 + c * 8;

    #pragma unroll 2
    for (int p = 0; p < 16; ++p) {
        const float* xp = xbase + (size_t)(p * 8 + r) * 4096;  // row stride = A*DE
        float4 xa = *(const float4*)(xp);
        float4 xb = *(const float4*)(xp + 4);
        float xv[8] = {xa.x, xa.y, xa.z, xa.w, xb.x, xb.y, xb.z, xb.w};

        float v[10];
        #pragma unroll
        for (int h = 0; h < 8; ++h) {
            float acc = 0.f;
            #pragma unroll
            for (int j = 0; j < 8; ++j) acc += xv[j] * gr[h][j];
            v[h] = acc;
        }
        float sm = 0.f, sq = 0.f;
        #pragma unroll
        for (int j = 0; j < 8; ++j) { sm += xv[j]; sq += xv[j] * xv[j]; }
        v[8] = sm; v[9] = sq;

        // Folding reduce-scatter butterfly across 32 lanes.
        const int lb0 = c & 1, lb1 = c & 2, lb2 = c & 4, lb3 = c & 8;
        float a0 = lb0 ? v[1] : v[0]; float q0 = lb0 ? v[0] : v[1];
        a0 += __shfl_xor(q0, 1, 32);
        float a1 = lb0 ? v[3] : v[2]; float q1 = lb0 ? v[2] : v[3];
        a1 += __shfl_xor(q1, 1, 32);
        float a2 = lb0 ? v[5] : v[4]; float q2 = lb0 ? v[4] : v[5];
        a2 += __shfl_xor(q2, 1, 32);
        float a3 = lb0 ? v[7] : v[6]; float q3 = lb0 ? v[6] : v[7];
        a3 += __shfl_xor(q3, 1, 32);
        float a4 = lb0 ? v[9] : v[8]; float q4 = lb0 ? v[8] : v[9];
        a4 += __shfl_xor(q4, 1, 32);
        float w0 = lb1 ? a1 : a0; float r0 = lb1 ? a0 : a1;
        w0 += __shfl_xor(r0, 2, 32);
        float w1 = lb1 ? a3 : a2; float r1 = lb1 ? a2 : a3;
        w1 += __shfl_xor(r1, 2, 32);
        float w2 = a4 + __shfl_xor(a4, 2, 32);
        float x0 = lb2 ? w1 : w0; float r2 = lb2 ? w0 : w1;
        x0 += __shfl_xor(r2, 4, 32);
        float x1 = w2 + __shfl_xor(w2, 4, 32);
        float y = lb3 ? x1 : x0; float r3 = lb3 ? x0 : x1;
        y += __shfl_xor(r3, 8, 32);
        y += __shfl_xor(y, 16, 32);
        const float smv = __shfl(y, 8, 32);
        const float sqv = __shfl(y, 9, 32);

        if (c < 8) {
            const float mu   = smv * (1.0f / 256.0f);
            const float var  = sqv * (1.0f / 256.0f) - mu * mu;
            const float rstd = 1.0f / sqrtf(var + LN_EPS_);
            float sc = (rstd * (y - mu * s0v) + s2v) * INV_SQRT_DHEAD;
            const int lidx = p * 8 + r;
            if (mrow[lidx] == 0) sc = -INFINITY;
            sbuf[c][lidx] = sc;
        }
    }
    __syncthreads();
    // coalesced write of the 8x128 score tile
    {
        const int h = t >> 5;
        const float* rowp = &sbuf[h][0];
        float4 vout = *(const float4*)(rowp + c * 4);
        const size_t off = (size_t)((b*8 + h) * 16 + a) * 4096 + n * 512 + lc * 128 + c * 4;
        *(float4*)(attn + off) = vout;
    }
}

// ---------------------------------------------------------------------------
// Kernel 3: softmax over 4096 per (b,h,a) row (2 rows/block, two 256-thread
// halves concurrently) + m_h = attn @ vals split over 8 waves.
// Block->row map is XCD-clustered: each XCD processes exactly one b's rows
// (2 XCDs per b), pinning that b's 1 MB vals chunk L2-resident.
// ---------------------------------------------------------------------------
__global__ __launch_bounds__(512) void k_softmax_mh(
    float* __restrict__ attn, const float* __restrict__ vals,
    float* __restrict__ mh)
{
    __shared__ float p0[4096];
    __shared__ float p1[4096];
    __shared__ float red[2][4];
    __shared__ float mpart[2][8][64];
    const int t = threadIdx.x;
    const int half = t >> 8;      // which row this half handles
    const int tt = t & 255;
    const int w = tt >> 6;        // wave within half
    // XCD-clustered bijective remap: j%8 -> XCD (round-robin dispatch)
    const int j = blockIdx.x;
    const int xcd = j & 7, slot = j >> 3;                    // 32 slots/XCD
    const int rp = (xcd >> 1) * 64 + (xcd & 1) * 32 + slot;  // row-pair, b = rp>>6
    const int row0 = rp * 2;
    const int row = row0 + half;
    const int b = row0 >> 7;      // 128 rows per b

    float* dst = attn + (size_t)row * 4096;
    float* pl = half ? p1 : p0;

    float lmax = -INFINITY;
    float4 v4[4];
    #pragma unroll
    for (int k = 0; k < 4; ++k) {
        float4 vv = ((const float4*)dst)[k * 256 + tt];
        v4[k] = vv;
        lmax = fmaxf(lmax, fmaxf(fmaxf(vv.x, vv.y), fmaxf(vv.z, vv.w)));
    }
    lmax = waveReduceMax(lmax);
    if ((tt & 63) == 0) red[half][w] = lmax;
    __syncthreads();
    const float mx = fmaxf(fmaxf(red[half][0], red[half][1]),
                           fmaxf(red[half][2], red[half][3]));
    __syncthreads();
    float lsum = 0.f;
    #pragma unroll
    for (int k = 0; k < 4; ++k) {
        float4 vv = v4[k];
        vv.x = __expf(vv.x - mx); vv.y = __expf(vv.y - mx);
        vv.z = __expf(vv.z - mx); vv.w = __expf(vv.w - mx);
        v4[k] = vv;
        lsum += vv.x + vv.y + vv.z + vv.w;
    }
    lsum = waveReduceSum(lsum);
    if ((tt & 63) == 0) red[half][w] = lsum;
    __syncthreads();
    const float inv = 1.0f / (red[half][0] + red[half][1] +
                              red[half][2] + red[half][3]);
    #pragma unroll
    for (int k = 0; k < 4; ++k) {
        float4 vv = v4[k];
        vv.x *= inv; vv.y *= inv; vv.z *= inv; vv.w *= inv;
        ((float4*)pl)[k * 256 + tt] = vv;
        ((float4*)dst)[k * 256 + tt] = vv;
    }
    __syncthreads();

    // m_h: 8 waves, each owning a 512-wide x-chunk; p broadcast from LDS,
    // vals coalesced (64 consecutive d per wave).
    const int ch = t >> 6, d = t & 63;
    const float* vb = vals + (size_t)b * 262144 + d;
    float acc0a = 0.f, acc0b = 0.f, acc1a = 0.f, acc1b = 0.f;
    const int x0 = ch * 512;
    #pragma unroll 16
    for (int x = x0; x < x0 + 512; x += 2) {
        const float va = vb[(size_t)x * 64];
        const float vc = vb[(size_t)(x + 1) * 64];
        acc0a += p0[x] * va;     acc0b += p0[x + 1] * vc;
        acc1a += p1[x] * va;     acc1b += p1[x + 1] * vc;
    }
    mpart[0][ch][d] = acc0a + acc0b;
    mpart[1][ch][d] = acc1a + acc1b;
    __syncthreads();
    if (t < 128) {
        const int rr = t >> 6, dd = t & 63;
        float s = 0.f;
        #pragma unroll
        for (int cc = 0; cc < 8; ++cc) s += mpart[rr][cc][dd];
        mh[(size_t)(row0 + rr) * 64 + dd] = s;
    }
}

// ---------------------------------------------------------------------------
// Kernel 4: hyperbolic epilogue -> curr_hyp[b][64]; one wave per a (1024 thr!)
// ---------------------------------------------------------------------------
__global__ __launch_bounds__(1024) void k_final(
    const float* __restrict__ mh, float* __restrict__ out)
{
    __shared__ float contrib[16][64];
    const int t = threadIdx.x;
    const int a = t >> 6, d = t & 63;
    const int b = blockIdx.x;
    float accY = 0.f;
    #pragma unroll
    for (int h = 0; h < 8; ++h) {
        const float m = mh[(size_t)((b*8 + h) * 16 + a) * 64 + d];
        const float ss = waveReduceSum(m * m);
        const float nm = sqrtf(ss);
        const float n1 = fmaxf(nm, 1e-15f);
        const float t1 = tanhf(n1);
        const float e  = t1 * m / n1;
        const float ne = t1 * nm / n1;
        const float n2 = fmaxf(ne, 1e-15f);
        const float u  = fminf(n2, 1.0f - 1e-5f);
        accY += atanhf(u) * e / n2;
    }
    const float ym = accY * 0.125f;
    const float ssy = waveReduceSum(ym * ym);
    const float nmy = sqrtf(ssy);
    const float n3 = fmaxf(nmy, 1e-15f);
    const float t3 = tanhf(n3);
    const float chv = t3 * ym / n3;
    const float nch = t3 * nmy / n3;
    const float nrm = fmaxf(nch, 1e-6f);
    const float sc = fminf((1.0f - 1e-5f) / nrm, 1.0f);
    contrib[a][d] = chv * sc;
    __syncthreads();
    if (t < 64) {
        float s = 0.f;
        #pragma unroll
        for (int a2 = 0; a2 < 16; ++a2) s += contrib[a2][t];
        out[b * 64 + t] = s * (1.0f / 16.0f);
    }
}

// ---------------------------------------------------------------------------
extern "C" void kernel_launch(void* const* d_in, const int* in_sizes, int n_in,
                              void* d_out, int out_size, void* d_ws, size_t ws_size,
                              hipStream_t stream) {
    const float* curr_rho  = (const float*)d_in[0];
    const float* demo_rho  = (const float*)d_in[1];
    const float* demo_hyp  = (const float*)d_in[2];
    const int*   demo_mask = (const int*)d_in[3];
    const float* Wq   = (const float*)d_in[4];
    const float* Wk   = (const float*)d_in[5];
    const float* lnqw = (const float*)d_in[6];
    const float* lnqb = (const float*)d_in[7];
    const float* lnkw = (const float*)d_in[8];
    const float* lnkb = (const float*)d_in[9];

    float* out  = (float*)d_out;
    float* attn = out + 256;                 // curr_hyp first (B*DH=256), then attn

    float* ws   = (float*)d_ws;
    float* g    = ws;                        // 131072 floats
    float* s0   = ws + 131072;               // 512
    float* s2   = ws + 131584;               // 512
    float* vals = ws + 132096;               // 1048576
    float* mh   = ws + 1180672;              // 32768

    hipLaunchKernelGGL(k_prep, dim3(512), dim3(256), 0, stream,
                       curr_rho, Wq, Wk, lnqw, lnqb, lnkw, lnkb, g, s0, s2);
    hipLaunchKernelGGL(k_scores_vals, dim3(6144), dim3(256), 0, stream,
                       demo_rho, demo_mask, g, s0, s2, demo_hyp, attn, vals);
    hipLaunchKernelGGL(k_softmax_mh, dim3(256), dim3(512), 0, stream, attn, vals, mh);
    hipLaunchKernelGGL(k_final, dim3(4), dim3(1024), 0, stream, mh, out);
}